// Round 6
// baseline (143.101 us; speedup 1.0000x reference)
//
#include <hip/hip_runtime.h>

// Problem constants (match reference)
constexpr int   Bsz = 32, Csz = 8, Hsz = 256, Wsz = 256;
constexpr int   HW  = Hsz * Wsz;            // 65536 pixels per plane
constexpr int   G   = Csz / 4;              // 2 groups
constexpr int   NBG = Bsz * G;              // 64 (b,g) slots
constexpr float MASK_WEIGHT = 0.7f;
constexpr float IM_WEIGHT   = 0.3f;
// sigmoid(x) > 0.7  <=>  x > ln(0.7/0.3)
constexpr float XTHRESH = 0.8472978603872037f;

constexpr int BLK   = 256;                                // 4 waves
constexpr int ITERS = 4;                                  // float4 groups per thread per plane
constexpr int PIX4_PER_BG   = HW / 4;                     // 16384 float4 per plane
constexpr int BLOCKS_PER_BG = PIX4_PER_BG / (BLK * ITERS);// 16
constexpr int NB = NBG * BLOCKS_PER_BG;                   // 1024 blocks

typedef float fvec4 __attribute__((ext_vector_type(4)));

// ws float layout (block-private slots -> no zero-init, no atomics):
//   [0..NB) bce | [NB..2NB) masked-sum | [2NB..3NB) count | [3NB..4NB) dsum

// s_waitcnt simm16 (gfx9 family): vmcnt[3:0]=bits3:0, expcnt=bits6:4,
// lgkmcnt=bits11:8, vmcnt[5:4]=bits15:14.  exp=7,lgkm=15 -> no wait on those.
#define WAITCNT_VM(n) __builtin_amdgcn_s_waitcnt(0x0F70 | ((n) & 0xF) | (((n) >> 4) << 14))

__global__ __launch_bounds__(256) void lp_mask_main(
    const float* __restrict__ out, const float* __restrict__ tar,
    float* __restrict__ ws)
{
    const int tid   = threadIdx.x;
    const int blk   = blockIdx.x;
    const int bg    = blk / BLOCKS_PER_BG;      // 0..63 (= b*G + g)
    const int chunk = blk % BLOCKS_PER_BG;

    const size_t base = (size_t)bg * 4 * HW;    // (b*C + g*4) * HW
    const fvec4* po = reinterpret_cast<const fvec4*>(out + base);
    const fvec4* pt = reinterpret_cast<const fvec4*>(tar + base);
    constexpr int P4 = HW / 4;                  // float4 per plane

    // Dynamic LDS: 2 buffers x 8 planes x 256 float4 = 64 KB.
    // slot(buf, p) base index = (buf*8 + p)*256
    extern __shared__ fvec4 lds[];

    const int lbase = (tid >> 6) * 64;          // this wave's 64-lane slot (wave-uniform)
    const int idx0  = chunk * (BLK * ITERS) + tid;

    // Stage iteration `it` into buffer `buf`: 8 x global_load_lds width=16.
    // LDS dest is wave-uniform base + lane*16 -> lane i lands at lbase+i,
    // which is exactly the slot thread (wave*64+i) reads. Barrier-free.
    auto stage = [&](int buf, int it) {
        const int idx = idx0 + it * BLK;
#pragma unroll
        for (int p = 0; p < 4; ++p)
            __builtin_amdgcn_global_load_lds(
                (const __attribute__((address_space(1))) void*)&po[idx + p * P4],
                (__attribute__((address_space(3))) void*)&lds[(buf * 8 + p) * 256 + lbase],
                16, 0, 0);
#pragma unroll
        for (int p = 0; p < 4; ++p)
            __builtin_amdgcn_global_load_lds(
                (const __attribute__((address_space(1))) void*)&pt[idx + p * P4],
                (__attribute__((address_space(3))) void*)&lds[((buf * 8 + 4 + p) * 256) + lbase],
                16, 0, 0);
    };

    float bce = 0.0f, msum = 0.0f, cnt = 0.0f, dsum = 0.0f;
    constexpr float LOG2E = 1.4426950408889634f;
    constexpr float LN2   = 0.6931471805599453f;

    stage(0, 0);

#pragma unroll
    for (int it = 0; it < ITERS; ++it) {
        const int buf = it & 1;
        if (it + 1 < ITERS) {
            stage(buf ^ 1, it + 1);
            WAITCNT_VM(8);                      // oldest 8 (current buf) done; next 8 in flight
        } else {
            WAITCNT_VM(0);
        }
        asm volatile("" ::: "memory");          // don't hoist LDS reads above the wait

        const fvec4 a0 = lds[(buf * 8 + 0) * 256 + tid];
        const fvec4 a1 = lds[(buf * 8 + 1) * 256 + tid];
        const fvec4 a2 = lds[(buf * 8 + 2) * 256 + tid];
        const fvec4 a3 = lds[(buf * 8 + 3) * 256 + tid];
        const fvec4 b0 = lds[(buf * 8 + 4) * 256 + tid];
        const fvec4 b1 = lds[(buf * 8 + 5) * 256 + tid];
        const fvec4 b2 = lds[(buf * 8 + 6) * 256 + tid];
        const fvec4 b3 = lds[(buf * 8 + 7) * 256 + tid];

#pragma unroll
        for (int e = 0; e < 4; ++e) {
            const float x  = a3[e];             // mask logit
            const float t  = b3[e];             // mask target
            const float d0 = a0[e] - b0[e];
            const float d1 = a1[e] - b1[e];
            const float d2 = a2[e] - b2[e];

            // t*log(sig(x)) + (1-t)*log(1-sig(x)) = t*x - softplus(x)
            const float ax = __builtin_fabsf(x);
            const float ex = __builtin_exp2f(-ax * LOG2E);            // exp(-|x|)
            const float sp = fmaxf(x, 0.0f) + __builtin_log2f(1.0f + ex) * LN2;
            bce += __builtin_fmaf(t, x, -sp);

            const float dn = __builtin_sqrtf(d0 * d0 + d1 * d1 + d2 * d2);
            dsum += dn;
            if (x > XTHRESH) {
                msum += dn;
                cnt  += (dn != 0.0f) ? 1.0f : 0.0f;
            }
        }
        asm volatile("" ::: "memory");          // keep next stage below these reads
    }

    // wave (64-lane) reduction
#pragma unroll
    for (int off = 32; off > 0; off >>= 1) {
        bce  += __shfl_down(bce,  off, 64);
        msum += __shfl_down(msum, off, 64);
        cnt  += __shfl_down(cnt,  off, 64);
        dsum += __shfl_down(dsum, off, 64);
    }

    __shared__ float s[4][4];                   // 4 waves x 4 quantities
    const int wave = tid >> 6, lane = tid & 63;
    if (lane == 0) {
        s[wave][0] = bce; s[wave][1] = msum; s[wave][2] = cnt; s[wave][3] = dsum;
    }
    __syncthreads();
    if (tid == 0) {
        float rb = 0.0f, rm = 0.0f, rc = 0.0f, rd = 0.0f;
#pragma unroll
        for (int w = 0; w < 4; ++w) {
            rb += s[w][0]; rm += s[w][1]; rc += s[w][2]; rd += s[w][3];
        }
        ws[blk]          = rb;                  // block-private: no atomics
        ws[NB + blk]     = rm;
        ws[2 * NB + blk] = rc;
        ws[3 * NB + blk] = rd;
    }
}

__global__ __launch_bounds__(64) void lp_mask_final(
    const float* __restrict__ ws, float* __restrict__ outp)
{
    const int t = threadIdx.x;                  // one thread per (b,g), 64 total
    constexpr int NPB = BLOCKS_PER_BG;          // 16 partials per (b,g)
    const fvec4* wb = reinterpret_cast<const fvec4*>(ws) + t * (NPB / 4);
    const fvec4* wm = reinterpret_cast<const fvec4*>(ws + NB) + t * (NPB / 4);
    const fvec4* wc = reinterpret_cast<const fvec4*>(ws + 2 * NB) + t * (NPB / 4);
    const fvec4* wd = reinterpret_cast<const fvec4*>(ws + 3 * NB) + t * (NPB / 4);

    float b = 0.0f, m = 0.0f, c = 0.0f, d = 0.0f;
#pragma unroll
    for (int i = 0; i < NPB / 4; ++i) {
        const fvec4 vb = wb[i], vm = wm[i], vc = wc[i], vd = wd[i];
        b += vb[0] + vb[1] + vb[2] + vb[3];
        m += vm[0] + vm[1] + vm[2] + vm[3];
        c += vc[0] + vc[1] + vc[2] + vc[3];
        d += vd[0] + vd[1] + vd[2] + vd[3];
    }

    float ps = (c > 0.0f) ? (m / fmaxf(c, 1.0f)) : (d / (float)HW);

#pragma unroll
    for (int off = 32; off > 0; off >>= 1) {
        ps += __shfl_down(ps, off, 64);
        b  += __shfl_down(b,  off, 64);
    }

    if (t == 0) {
        const float mask_mean = -b / ((float)G * (float)Bsz * (float)HW);
        const float nocs_mean = ps / (float)(Bsz * G);
        outp[0] = MASK_WEIGHT * mask_mean + IM_WEIGHT * nocs_mean;
    }
}

extern "C" void kernel_launch(void* const* d_in, const int* in_sizes, int n_in,
                              void* d_out, int out_size, void* d_ws, size_t ws_size,
                              hipStream_t stream) {
    const float* out = (const float*)d_in[0];
    const float* tar = (const float*)d_in[1];
    float* ws = (float*)d_ws;
    float* o  = (float*)d_out;

    lp_mask_main<<<NB, BLK, 65536, stream>>>(out, tar, ws);  // 64 KB dynamic LDS
    lp_mask_final<<<1, 64, 0, stream>>>(ws, o);
}

// Round 7
// 138.791 us; speedup vs baseline: 1.0311x; 1.0311x over previous
//
#include <hip/hip_runtime.h>

// Problem constants (match reference)
constexpr int   Bsz = 32, Csz = 8, Hsz = 256, Wsz = 256;
constexpr int   HW  = Hsz * Wsz;            // 65536 pixels per plane
constexpr int   G   = Csz / 4;              // 2 groups
constexpr int   NBG = Bsz * G;              // 64 (b,g) slots
constexpr float MASK_WEIGHT = 0.7f;
constexpr float IM_WEIGHT   = 0.3f;
// sigmoid(x) > 0.7  <=>  x > ln(0.7/0.3)
constexpr float XTHRESH = 0.8472978603872037f;

constexpr int BLK = 256;                                  // 4 waves
constexpr int PIX4_PER_BG   = HW / 4;                     // 16384 float4 per plane
constexpr int BLOCKS_PER_BG = PIX4_PER_BG / BLK;          // 64 (ITERS=1)
constexpr int NB = NBG * BLOCKS_PER_BG;                   // 4096 blocks (16/CU)

typedef float fvec4 __attribute__((ext_vector_type(4)));

// ws float layout (block-private slots -> no zero-init, no atomics):
//   [0..NB) bce | [NB..2NB) masked-sum | [2NB..3NB) count | [3NB..4NB) dsum

__global__ __launch_bounds__(256) void lp_mask_main(
    const float* __restrict__ out, const float* __restrict__ tar,
    float* __restrict__ ws)
{
    const int tid   = threadIdx.x;
    const int blk   = blockIdx.x;
    const int bg    = blk / BLOCKS_PER_BG;      // 0..63 (= b*G + g)
    const int chunk = blk % BLOCKS_PER_BG;

    const size_t base = (size_t)bg * 4 * HW;    // (b*C + g*4) * HW
    const fvec4* po = reinterpret_cast<const fvec4*>(out + base);
    const fvec4* pt = reinterpret_cast<const fvec4*>(tar + base);
    constexpr int P4 = HW / 4;                  // float4 per plane

    const int idx = chunk * BLK + tid;

    // Single 8-load nontemporal burst per thread (no intra-thread serialize
    // point); concurrency comes from 16 blocks/CU x 4 waves.
    const fvec4 a0 = __builtin_nontemporal_load(&po[idx]);
    const fvec4 a1 = __builtin_nontemporal_load(&po[idx + P4]);
    const fvec4 a2 = __builtin_nontemporal_load(&po[idx + 2 * P4]);
    const fvec4 a3 = __builtin_nontemporal_load(&po[idx + 3 * P4]);
    const fvec4 b0 = __builtin_nontemporal_load(&pt[idx]);
    const fvec4 b1 = __builtin_nontemporal_load(&pt[idx + P4]);
    const fvec4 b2 = __builtin_nontemporal_load(&pt[idx + 2 * P4]);
    const fvec4 b3 = __builtin_nontemporal_load(&pt[idx + 3 * P4]);

    float bce = 0.0f, msum = 0.0f, cnt = 0.0f, dsum = 0.0f;
    constexpr float LOG2E = 1.4426950408889634f;
    constexpr float LN2   = 0.6931471805599453f;

#pragma unroll
    for (int e = 0; e < 4; ++e) {
        const float x  = a3[e];                 // mask logit
        const float t  = b3[e];                 // mask target
        const float d0 = a0[e] - b0[e];
        const float d1 = a1[e] - b1[e];
        const float d2 = a2[e] - b2[e];

        // t*log(sig(x)) + (1-t)*log(1-sig(x)) = t*x - softplus(x)
        const float ax = __builtin_fabsf(x);
        const float ex = __builtin_exp2f(-ax * LOG2E);            // exp(-|x|)
        const float sp = fmaxf(x, 0.0f) + __builtin_log2f(1.0f + ex) * LN2;
        bce += __builtin_fmaf(t, x, -sp);

        const float dn = __builtin_sqrtf(d0 * d0 + d1 * d1 + d2 * d2);
        dsum += dn;
        if (x > XTHRESH) {
            msum += dn;
            cnt  += (dn != 0.0f) ? 1.0f : 0.0f;
        }
    }

    // wave (64-lane) reduction
#pragma unroll
    for (int off = 32; off > 0; off >>= 1) {
        bce  += __shfl_down(bce,  off, 64);
        msum += __shfl_down(msum, off, 64);
        cnt  += __shfl_down(cnt,  off, 64);
        dsum += __shfl_down(dsum, off, 64);
    }

    __shared__ float s[4][4];                   // 4 waves x 4 quantities
    const int wave = tid >> 6, lane = tid & 63;
    if (lane == 0) {
        s[wave][0] = bce; s[wave][1] = msum; s[wave][2] = cnt; s[wave][3] = dsum;
    }
    __syncthreads();
    if (tid == 0) {
        float rb = 0.0f, rm = 0.0f, rc = 0.0f, rd = 0.0f;
#pragma unroll
        for (int w = 0; w < 4; ++w) {
            rb += s[w][0]; rm += s[w][1]; rc += s[w][2]; rd += s[w][3];
        }
        ws[blk]          = rb;                  // block-private: no atomics
        ws[NB + blk]     = rm;
        ws[2 * NB + blk] = rc;
        ws[3 * NB + blk] = rd;
    }
}

__global__ __launch_bounds__(64) void lp_mask_final(
    const float* __restrict__ ws, float* __restrict__ outp)
{
    const int t = threadIdx.x;                  // one thread per (b,g), 64 total
    constexpr int NPB = BLOCKS_PER_BG;          // 64 partials per (b,g)
    const fvec4* wb = reinterpret_cast<const fvec4*>(ws) + t * (NPB / 4);
    const fvec4* wm = reinterpret_cast<const fvec4*>(ws + NB) + t * (NPB / 4);
    const fvec4* wc = reinterpret_cast<const fvec4*>(ws + 2 * NB) + t * (NPB / 4);
    const fvec4* wd = reinterpret_cast<const fvec4*>(ws + 3 * NB) + t * (NPB / 4);

    float b = 0.0f, m = 0.0f, c = 0.0f, d = 0.0f;
#pragma unroll
    for (int i = 0; i < NPB / 4; ++i) {
        const fvec4 vb = wb[i], vm = wm[i], vc = wc[i], vd = wd[i];
        b += vb[0] + vb[1] + vb[2] + vb[3];
        m += vm[0] + vm[1] + vm[2] + vm[3];
        c += vc[0] + vc[1] + vc[2] + vc[3];
        d += vd[0] + vd[1] + vd[2] + vd[3];
    }

    float ps = (c > 0.0f) ? (m / fmaxf(c, 1.0f)) : (d / (float)HW);

#pragma unroll
    for (int off = 32; off > 0; off >>= 1) {
        ps += __shfl_down(ps, off, 64);
        b  += __shfl_down(b,  off, 64);
    }

    if (t == 0) {
        const float mask_mean = -b / ((float)G * (float)Bsz * (float)HW);
        const float nocs_mean = ps / (float)(Bsz * G);
        outp[0] = MASK_WEIGHT * mask_mean + IM_WEIGHT * nocs_mean;
    }
}

extern "C" void kernel_launch(void* const* d_in, const int* in_sizes, int n_in,
                              void* d_out, int out_size, void* d_ws, size_t ws_size,
                              hipStream_t stream) {
    const float* out = (const float*)d_in[0];
    const float* tar = (const float*)d_in[1];
    float* ws = (float*)d_ws;
    float* o  = (float*)d_out;

    lp_mask_main<<<NB, BLK, 0, stream>>>(out, tar, ws);
    lp_mask_final<<<1, 64, 0, stream>>>(ws, o);
}